// Round 1
// baseline (428.389 us; speedup 1.0000x reference)
//
#include <hip/hip_runtime.h>

#define N_NODES 8192
#define IN_F 256
#define OUT_F 128
#define ALPHA 0.5f
#define JC 4
#define KCHUNK 2048            // N_NODES / JC
#define RK 128                 // k-window per round
#define ROUNDS 16              // KCHUNK / RK
#define RSTEPS 4               // 32-k MFMA steps per round

using short8 = __attribute__((ext_vector_type(8))) short;
using f32x4  = __attribute__((ext_vector_type(4))) float;

__device__ __forceinline__ unsigned int f2bf(float f){
  unsigned int u = __float_as_uint(f);
  u += 0x7fffu + ((u >> 16) & 1u);   // RNE
  return u >> 16;
}
__device__ __forceinline__ float bf2f(short s){
  return __uint_as_float(((unsigned int)(unsigned short)s) << 16);
}

// ---------------- K0: fused  h = x@W  ->  {f1, f2, P(bf16 frag-major)} -----
// h is never written to global: f1/f2 reduced from fp32 accumulators,
// bf16 pack done via LDS re-stage (reusing the x staging buffer).
__global__ __launch_bounds__(256) void k_hfp(const float* __restrict__ x,
                                             const float* __restrict__ W,
                                             const float* __restrict__ a,
                                             unsigned short* __restrict__ P,
                                             float* __restrict__ f1,
                                             float* __restrict__ f2){
  __shared__ float xs[16*IN_F];            // 16 KB; reused as hs[16][132]
  const int tid = threadIdx.x;
  const int bx = blockIdx.x;
  const int r0 = bx * 16;
  const float4* xg = (const float4*)(x + (size_t)r0*IN_F);
  float4* xl = (float4*)xs;
  #pragma unroll
  for(int i=0;i<4;i++) xl[tid + i*256] = xg[tid + i*256];
  __syncthreads();
  const int wave = tid >> 6, lane = tid & 63;
  float2 acc[4];
  #pragma unroll
  for(int j=0;j<4;j++){ acc[j].x = 0.f; acc[j].y = 0.f; }
  const float2* Wp = (const float2*)W;
  for(int k4=0;k4<IN_F;k4+=4){
    float4 xq[4];
    #pragma unroll
    for(int j=0;j<4;j++) xq[j] = *(const float4*)&xs[(wave*4+j)*IN_F + k4];
    #pragma unroll
    for(int kk=0;kk<4;kk++){
      float2 wv = Wp[(size_t)(k4+kk)*64 + lane];
      #pragma unroll
      for(int j=0;j<4;j++){
        float xv = kk==0?xq[j].x : kk==1?xq[j].y : kk==2?xq[j].z : xq[j].w;
        acc[j].x += xv*wv.x; acc[j].y += xv*wv.y;
      }
    }
  }
  // ---- f1 = h@a1, f2 = h@a2 from fp32 accumulators ----
  float2 av1 = ((const float2*)a)[lane];
  float2 av2 = ((const float2*)(a + OUT_F))[lane];
  #pragma unroll
  for(int j=0;j<4;j++){
    float s1 = acc[j].x*av1.x + acc[j].y*av1.y;
    float s2 = acc[j].x*av2.x + acc[j].y*av2.y;
    #pragma unroll
    for(int off=32; off; off>>=1){
      s1 += __shfl_down(s1, off);
      s2 += __shfl_down(s2, off);
    }
    if(lane == 0){ f1[r0 + wave*4 + j] = s1; f2[r0 + wave*4 + j] = s2; }
  }
  // ---- pack bf16 fragment-major into P via LDS re-stage ----
  // P short idx ((kb*8+c)*64 + q*16 + n)*8 + t = bf16(h[kb*32+q*8+t][c*16+n])
  __syncthreads();                         // all waves done reading xs
  #pragma unroll
  for(int j=0;j<4;j++) *(float2*)&xs[(wave*4+j)*132 + lane*2] = acc[j];
  __syncthreads();
  const int kb = bx >> 1, half = bx & 1;   // this block = rows [r0, r0+16) = half of kb's 32
  const int c = tid >> 5, ql = (tid >> 4) & 1, n = tid & 15;
  short8 v;
  #pragma unroll
  for(int t=0;t<8;t++) v[t] = (short)f2bf(xs[(ql*8+t)*132 + c*16 + n]);
  *(short8*)(P + ((size_t)((kb*8 + c)*64 + half*32 + ql*16 + n))*8) = v;
}

// ---------------- K1: fused masked-exp + attn@h -> per-chunk partials ------
// grid (JC=4, 128) x 256 thr, 2 blocks/CU. 64-row x 2048-col blocks.
// adj register double-buffer: round rd+1's 8 int4 loads are issued before the
// MFMA barrier so the HBM stream stays in flight through the MFMA phase.
__global__ __launch_bounds__(256, 2) void k_attn(const int* __restrict__ adj,
    const unsigned short* __restrict__ P,
    const float* __restrict__ f1, const float* __restrict__ f2,
    float* __restrict__ part, float* __restrict__ denp){
  __shared__ __align__(16) unsigned short Alds[64*RK];   // 16 KB swizzled [row][k]
  __shared__ __align__(16) short Blds[RK*OUT_F];         // 32 KB fragment-major
  __shared__ float f1s[64];
  const int tid = threadIdx.x;
  const int wave = tid >> 6, lane = tid & 63;
  const int m = lane & 15, q = lane >> 4;
  const int jc = blockIdx.x;                 // linear id % 4 -> XCD-spread
  const int r0b = blockIdx.y * 64;
  const int jb = jc * KCHUNK;
  const int kb0 = jc * (KCHUNK/32);
  // staging coords: thread covers rows {i*8+srow}, k-cols [sc0, sc0+4)
  const int srow = tid >> 5;                 // 0..7
  const int sc0  = (tid & 31) * 4;           // 0..124
  const int swz  = ((((sc0 >> 3) ^ srow) << 4) | ((sc0 & 4) << 1));

  if(tid < 64) f1s[tid] = f1[r0b + tid];

  f32x4 acc0[8];
  #pragma unroll
  for(int c=0;c<8;c++) acc0[c] = (f32x4){0,0,0,0};
  float den0 = 0.f;

  const char* Ab = (const char*)Alds;
  char* Aw = (char*)Alds + swz;
  const int mw = m & 7;
  const int rg0 = wave*16 + m;

  // preload round 0 adj into regs
  const size_t rowstride = (size_t)N_NODES * 4;
  const char* ap0 = (const char*)adj + (((size_t)(r0b + srow)*N_NODES + jb + sc0) << 2);
  int4 adjv[8];
  #pragma unroll
  for(int i=0;i<8;i++) adjv[i] = *(const int4*)(ap0 + (size_t)i*8*rowstride);
  float4 fv = *(const float4*)(f2 + jb + sc0);

  __syncthreads();                           // f1s ready

  for(int rd=0; rd<ROUNDS; rd++){
    // ---- B-tile: 32KB linear memcpy from P (L2-resident per XCD) ----
    const int4* Pb = (const int4*)(P + ((size_t)(kb0 + rd*4) << 12));
    int4* Bl4 = (int4*)Blds;
    #pragma unroll
    for(int i=0;i<8;i++) Bl4[i*256 + tid] = Pb[i*256 + tid];
    // ---- A-tile: w = mask*exp from preloaded regs -> swizzled LDS ----
    #pragma unroll
    for(int i=0;i<8;i++){
      int4 av = adjv[i];
      float f1v = f1s[i*8 + srow];
      float t0 = f1v + fv.x, t1 = f1v + fv.y, t2 = f1v + fv.z, t3 = f1v + fv.w;
      t0 = t0 > 0.f ? t0 : ALPHA*t0;  t1 = t1 > 0.f ? t1 : ALPHA*t1;
      t2 = t2 > 0.f ? t2 : ALPHA*t2;  t3 = t3 > 0.f ? t3 : ALPHA*t3;
      float w0 = av.x > 0 ? __expf(t0) : 0.f;
      float w1 = av.y > 0 ? __expf(t1) : 0.f;
      float w2 = av.z > 0 ? __expf(t2) : 0.f;
      float w3 = av.w > 0 ? __expf(t3) : 0.f;
      uint2 pk;
      pk.x = f2bf(w0) | (f2bf(w1) << 16);
      pk.y = f2bf(w2) | (f2bf(w3) << 16);
      *(uint2*)(Aw + (i*8 + srow)*(RK*2)) = pk;
    }
    // ---- prefetch round rd+1 adj + f2 (in flight across MFMA phase) ----
    const int rdn = (rd+1 < ROUNDS) ? rd+1 : rd;      // clamped redundant reload on last
    const char* apn = ap0 + (size_t)(rdn*RK) * 4;
    #pragma unroll
    for(int i=0;i<8;i++) adjv[i] = *(const int4*)(apn + (size_t)i*8*rowstride);
    fv = *(const float4*)(f2 + jb + rdn*RK + sc0);
    __syncthreads();
    // ---- MFMA phase: LDS only ----
    #pragma unroll
    for(int s=0;s<RSTEPS;s++){
      const int gq = ((s*4 + q) ^ mw) << 4;
      short8 A0 = *(const short8*)(Ab + rg0*(RK*2) + gq);
      #pragma unroll
      for(int t=0;t<8;t++) den0 += bf2f(A0[t]);
      const short8* Bl = (const short8*)Blds + s*512 + lane;
      #pragma unroll
      for(int c=0;c<8;c++){
        short8 Bf = Bl[c*64];
        acc0[c] = __builtin_amdgcn_mfma_f32_16x16x32_bf16(A0, Bf, acc0[c], 0,0,0);
      }
    }
    __syncthreads();
  }

  // den: lanes m, m+16, m+32, m+48 hold q-partials of row m
  den0 += __shfl_down(den0, 32); den0 += __shfl_down(den0, 16);
  const int r0w = r0b + wave*16;
  if(lane < 16) denp[(size_t)jc*N_NODES + r0w + lane] = den0;
  // C/D layout: col = c*16 + m, row = q*4 + reg (verified)
  float* pp = part + (size_t)jc*N_NODES*OUT_F;
  #pragma unroll
  for(int c=0;c<8;c++){
    #pragma unroll
    for(int reg=0;reg<4;reg++)
      pp[(size_t)(r0w + q*4 + reg)*OUT_F + c*16 + m] = acc0[c][reg];
  }
}

// ---------------- K2: out = elu(sum(parts)/sum(dens)) ----------------
__global__ __launch_bounds__(256) void k_out(const float* __restrict__ part,
    const float* __restrict__ denp, float* __restrict__ out){
  const int idx = blockIdx.x*256 + threadIdx.x;
  const int r = idx >> 7;
  float v = 0.f, d = 0.f;
  #pragma unroll
  for(int p=0;p<JC;p++){
    v += part[(size_t)p*N_NODES*OUT_F + idx];
    d += denp[(size_t)p*N_NODES + r];
  }
  v /= d;
  out[idx] = v > 0.f ? v : (__expf(v) - 1.f);
}

extern "C" void kernel_launch(void* const* d_in, const int* in_sizes, int n_in,
                              void* d_out, int out_size, void* d_ws, size_t ws_size,
                              hipStream_t stream){
  const float* x   = (const float*)d_in[0];
  const int*   adj = (const int*)d_in[1];
  const float* W   = (const float*)d_in[2];
  const float* a   = (const float*)d_in[3];
  char* ws = (char*)d_ws;
  unsigned short* P = (unsigned short*)ws;                 // 2 MiB
  float* f1         = (float*)(ws + (2u<<20));             // 32 KiB
  float* f2         = (float*)(ws + (2u<<20) + (32u<<10)); // 32 KiB
  float* part       = (float*)(ws + (4u<<20));             // 16 MiB
  float* denp       = (float*)(ws + (20u<<20));            // 128 KiB
  float* out        = (float*)d_out;

  k_hfp<<<512, 256, 0, stream>>>(x, W, a, P, f1, f2);
  k_attn<<<dim3(JC,128), 256, 0, stream>>>(adj, P, f1, f2, part, denp);
  k_out<<<(N_NODES*OUT_F)/256, 256, 0, stream>>>(part, denp, out);
}

// Round 2
// 398.883 us; speedup vs baseline: 1.0740x; 1.0740x over previous
//
#include <hip/hip_runtime.h>

#define N_NODES 8192
#define IN_F 256
#define OUT_F 128
#define ALPHA 0.5f
#define JC 4
#define KCHUNK 2048            // N_NODES / JC
#define RK 128                 // k-window per round
#define ROUNDS 16              // KCHUNK / RK
#define RSTEPS 4               // 32-k MFMA steps per round

using short8 = __attribute__((ext_vector_type(8))) short;
using f32x4  = __attribute__((ext_vector_type(4))) float;

__device__ __forceinline__ unsigned int f2bf(float f){
  unsigned int u = __float_as_uint(f);
  u += 0x7fffu + ((u >> 16) & 1u);   // RNE
  return u >> 16;
}
__device__ __forceinline__ float bf2f(short s){
  return __uint_as_float(((unsigned int)(unsigned short)s) << 16);
}

// ---------------- K0: fused  h = x@W  ->  {f1, f2, P(bf16 frag-major)} -----
// h is never written to global: f1/f2 reduced from fp32 accumulators,
// bf16 pack done via LDS re-stage (reusing the x staging buffer).
__global__ __launch_bounds__(256) void k_hfp(const float* __restrict__ x,
                                             const float* __restrict__ W,
                                             const float* __restrict__ a,
                                             unsigned short* __restrict__ P,
                                             float* __restrict__ f1,
                                             float* __restrict__ f2){
  __shared__ float xs[16*IN_F];            // 16 KB; reused as hs[16][132]
  const int tid = threadIdx.x;
  const int bx = blockIdx.x;
  const int r0 = bx * 16;
  const float4* xg = (const float4*)(x + (size_t)r0*IN_F);
  float4* xl = (float4*)xs;
  #pragma unroll
  for(int i=0;i<4;i++) xl[tid + i*256] = xg[tid + i*256];
  __syncthreads();
  const int wave = tid >> 6, lane = tid & 63;
  float2 acc[4];
  #pragma unroll
  for(int j=0;j<4;j++){ acc[j].x = 0.f; acc[j].y = 0.f; }
  const float2* Wp = (const float2*)W;
  for(int k4=0;k4<IN_F;k4+=4){
    float4 xq[4];
    #pragma unroll
    for(int j=0;j<4;j++) xq[j] = *(const float4*)&xs[(wave*4+j)*IN_F + k4];
    #pragma unroll
    for(int kk=0;kk<4;kk++){
      float2 wv = Wp[(size_t)(k4+kk)*64 + lane];
      #pragma unroll
      for(int j=0;j<4;j++){
        float xv = kk==0?xq[j].x : kk==1?xq[j].y : kk==2?xq[j].z : xq[j].w;
        acc[j].x += xv*wv.x; acc[j].y += xv*wv.y;
      }
    }
  }
  // ---- f1 = h@a1, f2 = h@a2 from fp32 accumulators ----
  float2 av1 = ((const float2*)a)[lane];
  float2 av2 = ((const float2*)(a + OUT_F))[lane];
  #pragma unroll
  for(int j=0;j<4;j++){
    float s1 = acc[j].x*av1.x + acc[j].y*av1.y;
    float s2 = acc[j].x*av2.x + acc[j].y*av2.y;
    #pragma unroll
    for(int off=32; off; off>>=1){
      s1 += __shfl_down(s1, off);
      s2 += __shfl_down(s2, off);
    }
    if(lane == 0){ f1[r0 + wave*4 + j] = s1; f2[r0 + wave*4 + j] = s2; }
  }
  // ---- pack bf16 fragment-major into P via LDS re-stage ----
  // P short idx ((kb*8+c)*64 + q*16 + n)*8 + t = bf16(h[kb*32+q*8+t][c*16+n])
  __syncthreads();                         // all waves done reading xs
  #pragma unroll
  for(int j=0;j<4;j++) *(float2*)&xs[(wave*4+j)*132 + lane*2] = acc[j];
  __syncthreads();
  const int kb = bx >> 1, half = bx & 1;   // this block = rows [r0, r0+16) = half of kb's 32
  const int c = tid >> 5, ql = (tid >> 4) & 1, n = tid & 15;
  short8 v;
  #pragma unroll
  for(int t=0;t<8;t++) v[t] = (short)f2bf(xs[(ql*8+t)*132 + c*16 + n]);
  *(short8*)(P + ((size_t)((kb*8 + c)*64 + half*32 + ql*16 + n))*8) = v;
}

// ---------------- K1: fused masked-exp + attn@h -> per-chunk partials ------
// grid (JC=4, 128) x 256 thr, 2 blocks/CU. 64-row x 2048-col blocks.
// Staging: adj int4 loads interleaved IN the exp/pack loop (latency overlaps
// the VALU work of earlier iterations; __syncthreads drains vmcnt anyway, so
// early-issue "prefetch" across the barrier is impossible at HIP level).
__global__ __launch_bounds__(256, 2) void k_attn(const int* __restrict__ adj,
    const unsigned short* __restrict__ P,
    const float* __restrict__ f1, const float* __restrict__ f2,
    float* __restrict__ part, float* __restrict__ denp){
  __shared__ __align__(16) unsigned short Alds[64*RK];   // 16 KB swizzled [row][k]
  __shared__ __align__(16) short Blds[RK*OUT_F];         // 32 KB fragment-major
  __shared__ float f1s[64];
  const int tid = threadIdx.x;
  const int wave = tid >> 6, lane = tid & 63;
  const int m = lane & 15, q = lane >> 4;
  const int jc = blockIdx.x;                 // linear id % 4 -> XCD-spread
  const int r0b = blockIdx.y * 64;
  const int jb = jc * KCHUNK;
  const int kb0 = jc * (KCHUNK/32);
  // staging coords: thread covers rows {i*8+srow}, k-cols [sc0, sc0+4)
  const int srow = tid >> 5;                 // 0..7
  const int sc0  = (tid & 31) * 4;           // 0..124
  const int swz  = ((((sc0 >> 3) ^ srow) << 4) | ((sc0 & 4) << 1));

  if(tid < 64) f1s[tid] = f1[r0b + tid];

  f32x4 acc0[8];
  #pragma unroll
  for(int c=0;c<8;c++) acc0[c] = (f32x4){0,0,0,0};
  float den0 = 0.f;

  const char* Ab = (const char*)Alds;
  char* Aw = (char*)Alds + swz;
  const int mw = m & 7;
  const int rg0 = wave*16 + m;

  __syncthreads();                           // f1s ready

  for(int rd=0; rd<ROUNDS; rd++){
    const int kbase = jb + rd*RK;
    // ---- B-tile: 32KB linear memcpy from P (L2-resident per XCD) ----
    const int4* Pb = (const int4*)(P + ((size_t)(kb0 + rd*4) << 12));
    int4* Bl4 = (int4*)Blds;
    #pragma unroll
    for(int i=0;i<8;i++) Bl4[i*256 + tid] = Pb[i*256 + tid];
    // ---- A-tile: linear adj read -> w -> swizzled LDS ----
    float4 fv = *(const float4*)(f2 + kbase + sc0);
    const char* ap = (const char*)adj + (((size_t)(r0b + srow)*N_NODES + kbase + sc0) << 2);
    #pragma unroll
    for(int i=0;i<8;i++){
      int4 av = *(const int4*)(ap + ((size_t)i*8*N_NODES << 2));
      float f1v = f1s[i*8 + srow];
      float t0 = f1v + fv.x, t1 = f1v + fv.y, t2 = f1v + fv.z, t3 = f1v + fv.w;
      t0 = t0 > 0.f ? t0 : ALPHA*t0;  t1 = t1 > 0.f ? t1 : ALPHA*t1;
      t2 = t2 > 0.f ? t2 : ALPHA*t2;  t3 = t3 > 0.f ? t3 : ALPHA*t3;
      float w0 = av.x > 0 ? __expf(t0) : 0.f;
      float w1 = av.y > 0 ? __expf(t1) : 0.f;
      float w2 = av.z > 0 ? __expf(t2) : 0.f;
      float w3 = av.w > 0 ? __expf(t3) : 0.f;
      uint2 pk;
      pk.x = f2bf(w0) | (f2bf(w1) << 16);
      pk.y = f2bf(w2) | (f2bf(w3) << 16);
      *(uint2*)(Aw + (i*8 + srow)*(RK*2)) = pk;
    }
    __syncthreads();
    // ---- MFMA phase: LDS only ----
    #pragma unroll
    for(int s=0;s<RSTEPS;s++){
      const int gq = ((s*4 + q) ^ mw) << 4;
      short8 A0 = *(const short8*)(Ab + rg0*(RK*2) + gq);
      #pragma unroll
      for(int t=0;t<8;t++) den0 += bf2f(A0[t]);
      const short8* Bl = (const short8*)Blds + s*512 + lane;
      #pragma unroll
      for(int c=0;c<8;c++){
        short8 Bf = Bl[c*64];
        acc0[c] = __builtin_amdgcn_mfma_f32_16x16x32_bf16(A0, Bf, acc0[c], 0,0,0);
      }
    }
    __syncthreads();
  }

  // den: lanes m, m+16, m+32, m+48 hold q-partials of row m
  den0 += __shfl_down(den0, 32); den0 += __shfl_down(den0, 16);
  const int r0w = r0b + wave*16;
  if(lane < 16) denp[(size_t)jc*N_NODES + r0w + lane] = den0;
  // C/D layout: col = c*16 + m, row = q*4 + reg (verified)
  float* pp = part + (size_t)jc*N_NODES*OUT_F;
  #pragma unroll
  for(int c=0;c<8;c++){
    #pragma unroll
    for(int reg=0;reg<4;reg++)
      pp[(size_t)(r0w + q*4 + reg)*OUT_F + c*16 + m] = acc0[c][reg];
  }
}

// ---------------- K2: out = elu(sum(parts)/sum(dens)) ----------------
__global__ __launch_bounds__(256) void k_out(const float* __restrict__ part,
    const float* __restrict__ denp, float* __restrict__ out){
  const int idx = blockIdx.x*256 + threadIdx.x;
  const int r = idx >> 7;
  float v = 0.f, d = 0.f;
  #pragma unroll
  for(int p=0;p<JC;p++){
    v += part[(size_t)p*N_NODES*OUT_F + idx];
    d += denp[(size_t)p*N_NODES + r];
  }
  v /= d;
  out[idx] = v > 0.f ? v : (__expf(v) - 1.f);
}

extern "C" void kernel_launch(void* const* d_in, const int* in_sizes, int n_in,
                              void* d_out, int out_size, void* d_ws, size_t ws_size,
                              hipStream_t stream){
  const float* x   = (const float*)d_in[0];
  const int*   adj = (const int*)d_in[1];
  const float* W   = (const float*)d_in[2];
  const float* a   = (const float*)d_in[3];
  char* ws = (char*)d_ws;
  unsigned short* P = (unsigned short*)ws;                 // 2 MiB
  float* f1         = (float*)(ws + (2u<<20));             // 32 KiB
  float* f2         = (float*)(ws + (2u<<20) + (32u<<10)); // 32 KiB
  float* part       = (float*)(ws + (4u<<20));             // 16 MiB
  float* denp       = (float*)(ws + (20u<<20));            // 128 KiB
  float* out        = (float*)d_out;

  k_hfp<<<512, 256, 0, stream>>>(x, W, a, P, f1, f2);
  k_attn<<<dim3(JC,128), 256, 0, stream>>>(adj, P, f1, f2, part, denp);
  k_out<<<(N_NODES*OUT_F)/256, 256, 0, stream>>>(part, denp, out);
}